// Round 1
// baseline (99.626 us; speedup 1.0000x reference)
//
#include <hip/hip_runtime.h>
#include <hip/hip_bf16.h>
#include <cstdint>

// Problem: B=8, N=1024, C=256, H=8, D=64.
// out[b,i,o] = sum_{h,d} V[b,i,h,d] * w[b,i,h] * Wout[o,h,d]
// w[b,i,h]   = sum_j exp(S_ij)/d_j ;  S = Q K^T / 8 ; d_j = sum_i exp(S_ij)

typedef __attribute__((ext_vector_type(8))) short bf16x8;
typedef __attribute__((ext_vector_type(4))) float f32x4;

static __device__ __forceinline__ short f2b(float f) {
  union { float f; uint32_t u; } x; x.f = f;
  uint32_t u = x.u;
  uint32_t r = (u + 0x7fffu + ((u >> 16) & 1u)) >> 16;
  return (short)(r & 0xffffu);
}
static __device__ __forceinline__ float b2f(short s) {
  union { uint32_t u; float f; } x; x.u = ((uint32_t)(uint16_t)s) << 16;
  return x.f;
}

#define MFMA(a, b, c) __builtin_amdgcn_mfma_f32_16x16x32_bf16((a), (b), (c), 0, 0, 0)

// ---------------------------------------------------------------------------
// Kernel 1: QKV projection. grid (24, 8, 8) = (ntile over 3*512, mtile, b)
// C[b, i, n] = sum_c F[b,i,c] * W[c, n]   (W is (256, 512), n = h*64+d)
// ---------------------------------------------------------------------------
__global__ __launch_bounds__(256) void k_qkv(
    const float* __restrict__ F, const float* __restrict__ Wq,
    const float* __restrict__ Wk, const float* __restrict__ Wv,
    short* __restrict__ Qo, short* __restrict__ Ko, short* __restrict__ Vo)
{
  const int nt  = blockIdx.x;          // 0..23
  const int mt  = blockIdx.y;          // 0..7
  const int b   = blockIdx.z;          // 0..7
  const int mat = nt >> 3;             // 0=q 1=k 2=v
  const int n0  = (nt & 7) * 64;
  const int m0  = mt * 128;
  const float* W = (mat == 0) ? Wq : (mat == 1) ? Wk : Wv;
  short* O       = (mat == 0) ? Qo : (mat == 1) ? Ko : Vo;

  __shared__ short As[128][72];        // A tile, BK=64, +8 pad
  __shared__ short Bs[64][264];        // full K=256 of the 64-col B panel, +8 pad

  const int t  = threadIdx.x;
  const int wv = t >> 6;
  const int l  = t & 63;
  const int lo = l & 15;
  const int hi = l >> 4;

  // Stage B panel once: Bs[n][k] = W[k][n0+n]  (transpose at staging)
#pragma unroll
  for (int it = 0; it < 16; ++it) {
    int idx = t + it * 256;            // 0..4095
    int k   = idx >> 4;                // 0..255
    int c4  = idx & 15;
    const float4 v = *(const float4*)(W + (size_t)k * 512 + n0 + c4 * 4);
    Bs[c4 * 4 + 0][k] = f2b(v.x);
    Bs[c4 * 4 + 1][k] = f2b(v.y);
    Bs[c4 * 4 + 2][k] = f2b(v.z);
    Bs[c4 * 4 + 3][k] = f2b(v.w);
  }

  f32x4 acc[2][4];
#pragma unroll
  for (int i = 0; i < 2; ++i)
#pragma unroll
    for (int j = 0; j < 4; ++j) acc[i][j] = (f32x4){0.f, 0.f, 0.f, 0.f};

  for (int s = 0; s < 4; ++s) {        // K steps of 64
    const int k0 = s * 64;
    __syncthreads();                   // first iter also covers Bs staging
#pragma unroll
    for (int it = 0; it < 8; ++it) {
      int idx = t + it * 256;          // 0..2047
      int r   = idx >> 4;              // 0..127
      int c4  = idx & 15;
      const float4 v = *(const float4*)(F + (size_t)(b * 1024 + m0 + r) * 256 + k0 + c4 * 4);
      short4 s4;
      s4.x = f2b(v.x); s4.y = f2b(v.y); s4.z = f2b(v.z); s4.w = f2b(v.w);
      *(short4*)&As[r][c4 * 4] = s4;
    }
    __syncthreads();

    bf16x8 bfr[4][2];
#pragma unroll
    for (int fc = 0; fc < 4; ++fc)
#pragma unroll
      for (int kk = 0; kk < 2; ++kk)
        bfr[fc][kk] = *(const bf16x8*)&Bs[fc * 16 + lo][k0 + kk * 32 + hi * 8];
#pragma unroll
    for (int fr = 0; fr < 2; ++fr) {
#pragma unroll
      for (int kk = 0; kk < 2; ++kk) {
        bf16x8 a = *(const bf16x8*)&As[wv * 32 + fr * 16 + lo][kk * 32 + hi * 8];
#pragma unroll
        for (int fc = 0; fc < 4; ++fc)
          acc[fr][fc] = MFMA(a, bfr[fc][kk], acc[fr][fc]);
      }
    }
  }

#pragma unroll
  for (int fr = 0; fr < 2; ++fr)
#pragma unroll
    for (int fc = 0; fc < 4; ++fc)
#pragma unroll
      for (int r = 0; r < 4; ++r) {
        int i = m0 + wv * 32 + fr * 16 + hi * 4 + r;
        int n = n0 + fc * 16 + lo;
        O[(size_t)(b * 1024 + i) * 512 + n] = f2b(acc[fr][fc][r]);
      }
}

// ---------------------------------------------------------------------------
// Kernel 2: column denominators d_j = sum_i exp(S_ij). grid (16, 8, 8) = (jb, h, b)
// ---------------------------------------------------------------------------
__global__ __launch_bounds__(256) void k_colsum(
    const short* __restrict__ Q, const short* __restrict__ K,
    float* __restrict__ Dd)
{
  const int jb = blockIdx.x;
  const int h  = blockIdx.y;
  const int b  = blockIdx.z;
  const int j0 = jb * 64;

  __shared__ short Ks[64][72];
  __shared__ short Qs[64][72];

  const int t  = threadIdx.x;
  const int wv = t >> 6;
  const int l  = t & 63;
  const int lo = l & 15;
  const int hi = l >> 4;

  // stage K rows j0..j0+63 (head h) once
#pragma unroll
  for (int it = 0; it < 2; ++it) {
    int idx = t + it * 256;            // 0..511
    int r   = idx >> 3;                // 0..63
    int c8  = idx & 7;
    int4 v = *(const int4*)(K + ((size_t)(b * 1024 + j0 + r) * 512 + h * 64 + c8 * 8));
    *(int4*)&Ks[r][c8 * 8] = v;
  }

  float csum = 0.f;
  for (int is = 0; is < 16; ++is) {
    __syncthreads();                   // first iter also covers Ks staging
#pragma unroll
    for (int it = 0; it < 2; ++it) {
      int idx = t + it * 256;
      int r   = idx >> 3;
      int c8  = idx & 7;
      int4 v = *(const int4*)(Q + ((size_t)(b * 1024 + is * 64 + r) * 512 + h * 64 + c8 * 8));
      *(int4*)&Qs[r][c8 * 8] = v;
    }
    __syncthreads();

    bf16x8 b0 = *(const bf16x8*)&Ks[wv * 16 + lo][hi * 8];
    bf16x8 b1 = *(const bf16x8*)&Ks[wv * 16 + lo][32 + hi * 8];
#pragma unroll
    for (int f = 0; f < 4; ++f) {
      bf16x8 a0 = *(const bf16x8*)&Qs[f * 16 + lo][hi * 8];
      bf16x8 a1 = *(const bf16x8*)&Qs[f * 16 + lo][32 + hi * 8];
      f32x4 acc = (f32x4){0.f, 0.f, 0.f, 0.f};
      acc = MFMA(a0, b0, acc);
      acc = MFMA(a1, b1, acc);
#pragma unroll
      for (int r = 0; r < 4; ++r) csum += __expf(acc[r] * 0.125f);
    }
  }

  csum += __shfl_xor(csum, 16, 64);
  csum += __shfl_xor(csum, 32, 64);
  if (hi == 0)
    Dd[(size_t)(b * 8 + h) * 1024 + j0 + wv * 16 + lo] = csum;
}

// ---------------------------------------------------------------------------
// Kernel 3: w_i = sum_j exp(S_ij)/d_j. grid (16, 8, 8) = (ib, h, b)
// ---------------------------------------------------------------------------
__global__ __launch_bounds__(256) void k_rowsum(
    const short* __restrict__ Q, const short* __restrict__ K,
    const float* __restrict__ Dd, float* __restrict__ Wgt)
{
  const int ib = blockIdx.x;
  const int h  = blockIdx.y;
  const int b  = blockIdx.z;
  const int i0 = ib * 64;

  __shared__ short Qs[64][72];
  __shared__ short Ks[64][72];
  __shared__ float Rs[1024];

  const int t  = threadIdx.x;
  const int wv = t >> 6;
  const int l  = t & 63;
  const int lo = l & 15;
  const int hi = l >> 4;

  // reciprocal denominator table
  {
    const float4 dv = *(const float4*)(Dd + (size_t)(b * 8 + h) * 1024 + t * 4);
    Rs[t * 4 + 0] = 1.0f / dv.x;
    Rs[t * 4 + 1] = 1.0f / dv.y;
    Rs[t * 4 + 2] = 1.0f / dv.z;
    Rs[t * 4 + 3] = 1.0f / dv.w;
  }
  // stage Q rows i0..i0+63 once
#pragma unroll
  for (int it = 0; it < 2; ++it) {
    int idx = t + it * 256;
    int r   = idx >> 3;
    int c8  = idx & 7;
    int4 v = *(const int4*)(Q + ((size_t)(b * 1024 + i0 + r) * 512 + h * 64 + c8 * 8));
    *(int4*)&Qs[r][c8 * 8] = v;
  }

  float wacc[4] = {0.f, 0.f, 0.f, 0.f};
  for (int js = 0; js < 16; ++js) {
    __syncthreads();                   // first iter also covers Qs/Rs staging
#pragma unroll
    for (int it = 0; it < 2; ++it) {
      int idx = t + it * 256;
      int r   = idx >> 3;
      int c8  = idx & 7;
      int4 v = *(const int4*)(K + ((size_t)(b * 1024 + js * 64 + r) * 512 + h * 64 + c8 * 8));
      *(int4*)&Ks[r][c8 * 8] = v;
    }
    __syncthreads();

    bf16x8 a0 = *(const bf16x8*)&Qs[wv * 16 + lo][hi * 8];
    bf16x8 a1 = *(const bf16x8*)&Qs[wv * 16 + lo][32 + hi * 8];
#pragma unroll
    for (int f = 0; f < 4; ++f) {
      bf16x8 b0 = *(const bf16x8*)&Ks[f * 16 + lo][hi * 8];
      bf16x8 b1 = *(const bf16x8*)&Ks[f * 16 + lo][32 + hi * 8];
      f32x4 acc = (f32x4){0.f, 0.f, 0.f, 0.f};
      acc = MFMA(a0, b0, acc);
      acc = MFMA(a1, b1, acc);
      float rj = Rs[js * 64 + f * 16 + lo];
#pragma unroll
      for (int r = 0; r < 4; ++r) wacc[r] += __expf(acc[r] * 0.125f) * rj;
    }
  }

#pragma unroll
  for (int m = 1; m <= 8; m <<= 1)
#pragma unroll
    for (int r = 0; r < 4; ++r) wacc[r] += __shfl_xor(wacc[r], m, 64);

  if (lo == 0) {
#pragma unroll
    for (int r = 0; r < 4; ++r) {
      int i = i0 + wv * 16 + hi * 4 + r;
      Wgt[((size_t)(b * 1024) + i) * 8 + h] = wacc[r];
    }
  }
}

// ---------------------------------------------------------------------------
// Kernel 4: out = (V .* w) @ Wout^T. grid (4, 8, 8) = (ntile, mtile, b)
// M=1024(i), N=256(o), K=512(hd); K-step 64 == one head.
// ---------------------------------------------------------------------------
__global__ __launch_bounds__(256) void k_out(
    const short* __restrict__ V, const float* __restrict__ Wgt,
    const float* __restrict__ Wo, float* __restrict__ Out)
{
  const int n0 = blockIdx.x * 64;
  const int m0 = blockIdx.y * 128;
  const int b  = blockIdx.z;

  __shared__ short As[128][72];
  __shared__ short Bs[64][72];

  const int t  = threadIdx.x;
  const int wv = t >> 6;
  const int l  = t & 63;
  const int lo = l & 15;
  const int hi = l >> 4;

  f32x4 acc[2][4];
#pragma unroll
  for (int i = 0; i < 2; ++i)
#pragma unroll
    for (int j = 0; j < 4; ++j) acc[i][j] = (f32x4){0.f, 0.f, 0.f, 0.f};

  for (int s = 0; s < 8; ++s) {        // K-step == head s
    __syncthreads();
    // A' tile: rows m0..m0+127, cols = head s dims, scaled by w
#pragma unroll
    for (int it = 0; it < 4; ++it) {
      int idx = t + it * 256;          // 0..1023
      int r   = idx >> 3;              // 0..127
      int c8  = idx & 7;
      int4 raw = *(const int4*)(V + ((size_t)(b * 1024 + m0 + r) * 512 + s * 64 + c8 * 8));
      float wvs = Wgt[((size_t)(b * 1024) + m0 + r) * 8 + s];
      union { int4 v; short s[8]; } u; u.v = raw;
      union { int4 v; short s[8]; } o;
#pragma unroll
      for (int j = 0; j < 8; ++j) o.s[j] = f2b(b2f(u.s[j]) * wvs);
      *(int4*)&As[r][c8 * 8] = o.v;
    }
    // B tile: Bs[n][k] = Wo[n0+n][s*64+k]  (row-major in global, no transpose)
#pragma unroll
    for (int it = 0; it < 4; ++it) {
      int idx = t + it * 256;          // 0..1023
      int n   = idx >> 4;              // 0..63
      int c4  = idx & 15;
      const float4 v = *(const float4*)(Wo + (size_t)(n0 + n) * 512 + s * 64 + c4 * 4);
      short4 s4;
      s4.x = f2b(v.x); s4.y = f2b(v.y); s4.z = f2b(v.z); s4.w = f2b(v.w);
      *(short4*)&Bs[n][c4 * 4] = s4;
    }
    __syncthreads();

#pragma unroll
    for (int kk = 0; kk < 2; ++kk) {
      bf16x8 bfr[4];
#pragma unroll
      for (int fc = 0; fc < 4; ++fc)
        bfr[fc] = *(const bf16x8*)&Bs[fc * 16 + lo][kk * 32 + hi * 8];
#pragma unroll
      for (int fr = 0; fr < 2; ++fr) {
        bf16x8 a = *(const bf16x8*)&As[wv * 32 + fr * 16 + lo][kk * 32 + hi * 8];
#pragma unroll
        for (int fc = 0; fc < 4; ++fc)
          acc[fr][fc] = MFMA(a, bfr[fc], acc[fr][fc]);
      }
    }
  }

#pragma unroll
  for (int fr = 0; fr < 2; ++fr)
#pragma unroll
    for (int fc = 0; fc < 4; ++fc)
#pragma unroll
      for (int r = 0; r < 4; ++r) {
        int i = m0 + wv * 32 + fr * 16 + hi * 4 + r;
        int o = n0 + fc * 16 + lo;
        Out[(size_t)(b * 1024 + i) * 256 + o] = acc[fr][fc][r];
      }
}

// ---------------------------------------------------------------------------
extern "C" void kernel_launch(void* const* d_in, const int* in_sizes, int n_in,
                              void* d_out, int out_size, void* d_ws, size_t ws_size,
                              hipStream_t stream) {
  const float* F  = (const float*)d_in[0];
  const float* Wq = (const float*)d_in[1];
  const float* Wk = (const float*)d_in[2];
  const float* Wv = (const float*)d_in[3];
  const float* Wo = (const float*)d_in[4];
  float* out = (float*)d_out;

  char* ws = (char*)d_ws;
  short* Q  = (short*)(ws);                                  // 8 MB bf16
  short* K  = (short*)(ws + (size_t)(8  << 20));             // 8 MB
  short* V  = (short*)(ws + (size_t)(16 << 20));             // 8 MB
  float* Dd = (float*)(ws + (size_t)(24 << 20));             // 256 KB
  float* Wg = (float*)(ws + (size_t)(24 << 20) + (256 << 10)); // 256 KB

  k_qkv<<<dim3(24, 8, 8), 256, 0, stream>>>(F, Wq, Wk, Wv, Q, K, V);
  k_colsum<<<dim3(16, 8, 8), 256, 0, stream>>>(Q, K, Dd);
  k_rowsum<<<dim3(16, 8, 8), 256, 0, stream>>>(Q, K, Dd, Wg);
  k_out<<<dim3(4, 8, 8), 256, 0, stream>>>(V, Wg, Wo, out);
}

// Round 2
// 97.251 us; speedup vs baseline: 1.0244x; 1.0244x over previous
//
#include <hip/hip_runtime.h>
#include <hip/hip_bf16.h>
#include <cstdint>

// Problem: B=8, N=1024, C=256, H=8, D=64.
// out[b,i,o] = sum_{h,d} V[b,i,h,d] * w[b,i,h] * Wout[o,h,d]
// w[b,i,h]   = sum_j exp(S_ij)/d_j ;  S = Q K^T / 8 ; d_j = sum_i exp(S_ij)
// Scale fold: Wq' = Wq * 0.125*log2(e)  =>  exp(S/8) == exp2(Q'K^T) directly.

typedef __attribute__((ext_vector_type(8))) short bf16x8;
typedef __attribute__((ext_vector_type(4))) float f32x4;

#if __has_builtin(__builtin_amdgcn_exp2f)
#define EXP2(x) __builtin_amdgcn_exp2f(x)
#else
#define EXP2(x) exp2f(x)
#endif

static __device__ __forceinline__ uint32_t pk2(float x, float y) {
  union { __hip_bfloat162 h; uint32_t u; } c;
  c.h = __float22bfloat162_rn(float2{x, y});
  return c.u;
}
static __device__ __forceinline__ short cvt1(float f) {
  union { __hip_bfloat16 h; short s; } c;
  c.h = __float2bfloat16(f);
  return c.s;
}

#define MFMA(a, b, c) __builtin_amdgcn_mfma_f32_16x16x32_bf16((a), (b), (c), 0, 0, 0)

// ---------------------------------------------------------------------------
// Kernel 0: weight prep.
//  Wt[m][n][c] = bf16( W_m[c][n] * (m==0 ? 0.1803368801 : 1) )   (512 x 256)
//  Wob[o][k]   = bf16( Wo[o][k] )                                 (256 x 512)
// 65536 threads = 256 blocks x 256.
// ---------------------------------------------------------------------------
__global__ __launch_bounds__(256) void k_prep(
    const float* __restrict__ Wq, const float* __restrict__ Wk,
    const float* __restrict__ Wv, const float* __restrict__ Wo,
    short* __restrict__ Wt, short* __restrict__ Wob)
{
  const int t = blockIdx.x * 256 + threadIdx.x;
  if (t < 49152) {
    const int m  = t >> 14;
    const int r  = t & 16383;
    const int n  = r >> 5;     // 0..511
    const int c8 = r & 31;     // c = c8*8
    const float* W = (m == 0) ? Wq : (m == 1) ? Wk : Wv;
    const float scale = (m == 0) ? 0.18033688011112042f : 1.0f;
    short tmp[8];
#pragma unroll
    for (int j = 0; j < 8; ++j)
      tmp[j] = cvt1(W[(size_t)(c8 * 8 + j) * 512 + n] * scale);
    *(int4*)&Wt[(size_t)m * 131072 + n * 256 + c8 * 8] = *(int4*)tmp;
  } else {
    const int r  = t - 49152;  // 0..16383
    const int o  = r >> 6;     // 0..255
    const int k8 = r & 63;     // k = k8*8
    const float4 v0 = *(const float4*)(Wo + (size_t)o * 512 + k8 * 8);
    const float4 v1 = *(const float4*)(Wo + (size_t)o * 512 + k8 * 8 + 4);
    uint32_t u0 = pk2(v0.x, v0.y), u1 = pk2(v0.z, v0.w);
    uint32_t u2 = pk2(v1.x, v1.y), u3 = pk2(v1.z, v1.w);
    uint32_t tmp[4] = {u0, u1, u2, u3};
    *(uint4*)&Wob[(size_t)o * 512 + k8 * 8] = *(uint4*)tmp;
  }
}

// ---------------------------------------------------------------------------
// Kernel 1: fused QKV projection. grid (8, 8, 8) = (nt, mt, b)
// One A tile (128x64 per k-step) feeds all three weight panels.
// ---------------------------------------------------------------------------
__global__ __launch_bounds__(256) void k_qkv(
    const float* __restrict__ F, const short* __restrict__ Wt,
    short* __restrict__ Qo, short* __restrict__ Ko, short* __restrict__ Vo)
{
  const int n0 = blockIdx.x * 64;
  const int m0 = blockIdx.y * 128;
  const int b  = blockIdx.z;

  __shared__ short As[128][72];
  __shared__ short Bs[3][64][72];

  const int t  = threadIdx.x;
  const int wv = t >> 6;
  const int l  = t & 63;
  const int lo = l & 15;
  const int hi = l >> 4;

  f32x4 acc[3][2][4];
#pragma unroll
  for (int m = 0; m < 3; ++m)
#pragma unroll
    for (int i = 0; i < 2; ++i)
#pragma unroll
      for (int j = 0; j < 4; ++j) acc[m][i][j] = (f32x4){0.f, 0.f, 0.f, 0.f};

  for (int s = 0; s < 4; ++s) {        // K steps of 64
    const int k0 = s * 64;
    __syncthreads();
    // A tile: convert F fp32 -> bf16 (v_cvt_pk via __float22bfloat162_rn)
#pragma unroll
    for (int it = 0; it < 8; ++it) {
      int idx = t + it * 256;          // 0..2047
      int r   = idx >> 4;              // 0..127
      int c4  = idx & 15;
      const float4 v = *(const float4*)(F + (size_t)(b * 1024 + m0 + r) * 256 + k0 + c4 * 4);
      uint32_t u[2] = {pk2(v.x, v.y), pk2(v.z, v.w)};
      *(uint2*)&As[r][c4 * 4] = *(uint2*)u;
    }
    // B tiles: straight int4 copy from pre-transposed bf16 weights
#pragma unroll
    for (int m = 0; m < 3; ++m)
#pragma unroll
      for (int it = 0; it < 2; ++it) {
        int idx = t + it * 256;        // 0..511
        int n   = idx >> 3;            // 0..63
        int c8  = idx & 7;
        *(int4*)&Bs[m][n][c8 * 8] =
            *(const int4*)(Wt + (size_t)m * 131072 + (size_t)(n0 + n) * 256 + k0 + c8 * 8);
      }
    __syncthreads();

    bf16x8 a[2][2];
#pragma unroll
    for (int fr = 0; fr < 2; ++fr)
#pragma unroll
      for (int kk = 0; kk < 2; ++kk)
        a[fr][kk] = *(const bf16x8*)&As[wv * 32 + fr * 16 + lo][kk * 32 + hi * 8];

#pragma unroll
    for (int m = 0; m < 3; ++m)
#pragma unroll
      for (int kk = 0; kk < 2; ++kk)
#pragma unroll
        for (int fc = 0; fc < 4; ++fc) {
          bf16x8 bfr = *(const bf16x8*)&Bs[m][fc * 16 + lo][kk * 32 + hi * 8];
#pragma unroll
          for (int fr = 0; fr < 2; ++fr)
            acc[m][fr][fc] = MFMA(a[fr][kk], bfr, acc[m][fr][fc]);
        }
  }

#pragma unroll
  for (int m = 0; m < 3; ++m) {
    short* O = (m == 0) ? Qo : (m == 1) ? Ko : Vo;
#pragma unroll
    for (int fr = 0; fr < 2; ++fr)
#pragma unroll
      for (int fc = 0; fc < 4; ++fc)
#pragma unroll
        for (int r = 0; r < 4; ++r) {
          int i = m0 + wv * 32 + fr * 16 + hi * 4 + r;
          int n = n0 + fc * 16 + lo;
          O[(size_t)(b * 1024 + i) * 512 + n] = cvt1(acc[m][fr][fc][r]);
        }
  }
}

// ---------------------------------------------------------------------------
// Kernel 2: column denominators d_j = sum_i exp2(S'_ij). grid (16, 8, 8)
// ---------------------------------------------------------------------------
__global__ __launch_bounds__(256) void k_colsum(
    const short* __restrict__ Q, const short* __restrict__ K,
    float* __restrict__ Dd)
{
  const int jb = blockIdx.x;
  const int h  = blockIdx.y;
  const int b  = blockIdx.z;
  const int j0 = jb * 64;

  __shared__ short Ks[64][72];
  __shared__ short Qs[128][72];

  const int t  = threadIdx.x;
  const int wv = t >> 6;
  const int l  = t & 63;
  const int lo = l & 15;
  const int hi = l >> 4;

  // stage K rows once
#pragma unroll
  for (int it = 0; it < 2; ++it) {
    int idx = t + it * 256;
    int r   = idx >> 3;
    int c8  = idx & 7;
    *(int4*)&Ks[r][c8 * 8] =
        *(const int4*)(K + ((size_t)(b * 1024 + j0 + r) * 512 + h * 64 + c8 * 8));
  }
  __syncthreads();
  const bf16x8 b0 = *(const bf16x8*)&Ks[wv * 16 + lo][hi * 8];
  const bf16x8 b1 = *(const bf16x8*)&Ks[wv * 16 + lo][32 + hi * 8];

  float csum = 0.f;
  for (int is = 0; is < 8; ++is) {     // 128 i-rows per step
    __syncthreads();
#pragma unroll
    for (int it = 0; it < 4; ++it) {
      int idx = t + it * 256;          // 0..1023
      int r   = idx >> 3;              // 0..127
      int c8  = idx & 7;
      *(int4*)&Qs[r][c8 * 8] =
          *(const int4*)(Q + ((size_t)(b * 1024 + is * 128 + r) * 512 + h * 64 + c8 * 8));
    }
    __syncthreads();

#pragma unroll
    for (int f = 0; f < 8; ++f) {
      bf16x8 a0 = *(const bf16x8*)&Qs[f * 16 + lo][hi * 8];
      bf16x8 a1 = *(const bf16x8*)&Qs[f * 16 + lo][32 + hi * 8];
      f32x4 acc = (f32x4){0.f, 0.f, 0.f, 0.f};
      acc = MFMA(a0, b0, acc);
      acc = MFMA(a1, b1, acc);
#pragma unroll
      for (int r = 0; r < 4; ++r) csum += EXP2(acc[r]);
    }
  }

  csum += __shfl_xor(csum, 16, 64);
  csum += __shfl_xor(csum, 32, 64);
  if (hi == 0)
    Dd[(size_t)(b * 8 + h) * 1024 + j0 + wv * 16 + lo] = csum;
}

// ---------------------------------------------------------------------------
// Kernel 3: w_i = sum_j exp2(S'_ij)/d_j. grid (16, 8, 8)
// ---------------------------------------------------------------------------
__global__ __launch_bounds__(256) void k_rowsum(
    const short* __restrict__ Q, const short* __restrict__ K,
    const float* __restrict__ Dd, float* __restrict__ Wgt)
{
  const int ib = blockIdx.x;
  const int h  = blockIdx.y;
  const int b  = blockIdx.z;
  const int i0 = ib * 64;

  __shared__ short Qs[64][72];
  __shared__ short Ks[128][72];
  __shared__ float Rs[1024];

  const int t  = threadIdx.x;
  const int wv = t >> 6;
  const int l  = t & 63;
  const int lo = l & 15;
  const int hi = l >> 4;

  // reciprocal denominators
  {
    const float4 dv = *(const float4*)(Dd + (size_t)(b * 8 + h) * 1024 + t * 4);
    Rs[t * 4 + 0] = __builtin_amdgcn_rcpf(dv.x);
    Rs[t * 4 + 1] = __builtin_amdgcn_rcpf(dv.y);
    Rs[t * 4 + 2] = __builtin_amdgcn_rcpf(dv.z);
    Rs[t * 4 + 3] = __builtin_amdgcn_rcpf(dv.w);
  }
  // stage Q rows once
#pragma unroll
  for (int it = 0; it < 2; ++it) {
    int idx = t + it * 256;
    int r   = idx >> 3;
    int c8  = idx & 7;
    *(int4*)&Qs[r][c8 * 8] =
        *(const int4*)(Q + ((size_t)(b * 1024 + i0 + r) * 512 + h * 64 + c8 * 8));
  }
  __syncthreads();
  const bf16x8 a0 = *(const bf16x8*)&Qs[wv * 16 + lo][hi * 8];
  const bf16x8 a1 = *(const bf16x8*)&Qs[wv * 16 + lo][32 + hi * 8];

  float wacc[4] = {0.f, 0.f, 0.f, 0.f};
  for (int js = 0; js < 8; ++js) {     // 128 j-rows per step
    __syncthreads();
#pragma unroll
    for (int it = 0; it < 4; ++it) {
      int idx = t + it * 256;
      int r   = idx >> 3;              // 0..127
      int c8  = idx & 7;
      *(int4*)&Ks[r][c8 * 8] =
          *(const int4*)(K + ((size_t)(b * 1024 + js * 128 + r) * 512 + h * 64 + c8 * 8));
    }
    __syncthreads();

#pragma unroll
    for (int f = 0; f < 8; ++f) {
      bf16x8 b0 = *(const bf16x8*)&Ks[f * 16 + lo][hi * 8];
      bf16x8 b1 = *(const bf16x8*)&Ks[f * 16 + lo][32 + hi * 8];
      f32x4 acc = (f32x4){0.f, 0.f, 0.f, 0.f};
      acc = MFMA(a0, b0, acc);
      acc = MFMA(a1, b1, acc);
      float rj = Rs[js * 128 + f * 16 + lo];
#pragma unroll
      for (int r = 0; r < 4; ++r) wacc[r] = fmaf(EXP2(acc[r]), rj, wacc[r]);
    }
  }

#pragma unroll
  for (int m = 1; m <= 8; m <<= 1)
#pragma unroll
    for (int r = 0; r < 4; ++r) wacc[r] += __shfl_xor(wacc[r], m, 64);

  if (lo == 0) {
#pragma unroll
    for (int r = 0; r < 4; ++r) {
      int i = i0 + wv * 16 + hi * 4 + r;
      Wgt[((size_t)(b * 1024) + i) * 8 + h] = wacc[r];
    }
  }
}

// ---------------------------------------------------------------------------
// Kernel 4: out = (V .* w) @ Wob^T. grid (4, 16, 8) = (nt, mt, b)
// M-tile 64, N-tile 64, K-step 64 (= one head).
// ---------------------------------------------------------------------------
__global__ __launch_bounds__(256) void k_out(
    const short* __restrict__ V, const float* __restrict__ Wgt,
    const short* __restrict__ Wob, float* __restrict__ Out)
{
  const int n0 = blockIdx.x * 64;
  const int m0 = blockIdx.y * 64;
  const int b  = blockIdx.z;

  __shared__ short As[64][72];
  __shared__ short Bs[64][72];

  const int t  = threadIdx.x;
  const int wv = t >> 6;
  const int l  = t & 63;
  const int lo = l & 15;
  const int hi = l >> 4;

  f32x4 acc[4];
#pragma unroll
  for (int j = 0; j < 4; ++j) acc[j] = (f32x4){0.f, 0.f, 0.f, 0.f};

  for (int s = 0; s < 8; ++s) {        // K-step == head s
    __syncthreads();
    // A' tile: V rows scaled by w (unpack pair, mul, repack via cvt_pk)
#pragma unroll
    for (int it = 0; it < 2; ++it) {
      int idx = t + it * 256;          // 0..511
      int r   = idx >> 3;              // 0..63
      int c8  = idx & 7;
      int4 raw = *(const int4*)(V + ((size_t)(b * 1024 + m0 + r) * 512 + s * 64 + c8 * 8));
      float ws = Wgt[((size_t)(b * 1024) + m0 + r) * 8 + s];
      uint32_t* u = (uint32_t*)&raw;
      uint32_t o[4];
#pragma unroll
      for (int j = 0; j < 4; ++j) {
        float f0 = __uint_as_float(u[j] << 16) * ws;
        float f1 = __uint_as_float(u[j] & 0xffff0000u) * ws;
        o[j] = pk2(f0, f1);
      }
      *(uint4*)&As[r][c8 * 8] = *(uint4*)o;
    }
    // B tile: straight copy from pre-converted Wob
#pragma unroll
    for (int it = 0; it < 2; ++it) {
      int idx = t + it * 256;          // 0..511
      int n   = idx >> 3;              // 0..63
      int c8  = idx & 7;
      *(int4*)&Bs[n][c8 * 8] =
          *(const int4*)(Wob + (size_t)(n0 + n) * 512 + s * 64 + c8 * 8);
    }
    __syncthreads();

#pragma unroll
    for (int kk = 0; kk < 2; ++kk) {
      bf16x8 a = *(const bf16x8*)&As[wv * 16 + lo][kk * 32 + hi * 8];
#pragma unroll
      for (int fc = 0; fc < 4; ++fc) {
        bf16x8 bfr = *(const bf16x8*)&Bs[fc * 16 + lo][kk * 32 + hi * 8];
        acc[fc] = MFMA(a, bfr, acc[fc]);
      }
    }
  }

#pragma unroll
  for (int fc = 0; fc < 4; ++fc)
#pragma unroll
    for (int r = 0; r < 4; ++r) {
      int i = m0 + wv * 16 + hi * 4 + r;
      int o = n0 + fc * 16 + lo;
      Out[(size_t)(b * 1024 + i) * 256 + o] = acc[fc][r];
    }
}

// ---------------------------------------------------------------------------
extern "C" void kernel_launch(void* const* d_in, const int* in_sizes, int n_in,
                              void* d_out, int out_size, void* d_ws, size_t ws_size,
                              hipStream_t stream) {
  const float* F  = (const float*)d_in[0];
  const float* Wq = (const float*)d_in[1];
  const float* Wk = (const float*)d_in[2];
  const float* Wv = (const float*)d_in[3];
  const float* Wo = (const float*)d_in[4];
  float* out = (float*)d_out;

  char* ws = (char*)d_ws;
  short* Q   = (short*)(ws);                                     // 8 MB bf16
  short* K   = (short*)(ws + (size_t)(8  << 20));                // 8 MB
  short* V   = (short*)(ws + (size_t)(16 << 20));                // 8 MB
  float* Dd  = (float*)(ws + (size_t)(24 << 20));                // 256 KB
  float* Wg  = (float*)(ws + (size_t)(24 << 20) + (256 << 10));  // 256 KB
  short* Wt  = (short*)(ws + (size_t)(24 << 20) + (512 << 10));  // 768 KB
  short* Wob = (short*)(ws + (size_t)(24 << 20) + (1280 << 10)); // 256 KB

  k_prep  <<<dim3(256), 256, 0, stream>>>(Wq, Wk, Wv, Wo, Wt, Wob);
  k_qkv   <<<dim3(8, 8, 8), 256, 0, stream>>>(F, Wt, Q, K, V);
  k_colsum<<<dim3(16, 8, 8), 256, 0, stream>>>(Q, K, Dd);
  k_rowsum<<<dim3(16, 8, 8), 256, 0, stream>>>(Q, K, Dd, Wg);
  k_out   <<<dim3(4, 16, 8), 256, 0, stream>>>(V, Wg, Wob, out);
}